// Round 2
// baseline (79.319 us; speedup 1.0000x reference)
//
#include <hip/hip_runtime.h>

// FUME epipolar translation, fp32 in/out. B from in_sizes[3]; C,H,W = 4,128,128.
//
// R13: wave-per-pixel + TRANSPOSED cube [u][k].
//  - R11/R12 mapped 8 seg-waves x 64 pixels; trip = ceil(len/8) ~ 12-16 dependent
//    iterations per wave, each a fully-scattered 64-line gather (k-major layout:
//    one row per lane-step), grid 1024 blocks = 4/CU exact (no tail averaging).
//  - R13 maps ONE WAVE PER PIXEL: 64 lanes = 64 consecutive k-slots. Trips <= 2.
//    Grid 8192 blocks = 32/CU -> 8 scheduling rounds, imbalance averages out.
//  - Cube is stored TRANSPOSED [u][k] so consecutive k are contiguous 16B
//    entries; |du/dk| <= 1 (dominant axis) => a wave's 64 k-slots touch a few
//    row-runs of contiguous entries instead of 64 scattered rows.
//  Per-step math is bit-identical to R11/R12; only summation order changes
//  (xor-tree instead of seg-block order; f32 reorder noise ~1e-5 << fp16 path).
//
// Workspace (16B entries = {half2(tap0,tap1)}ch=0..3), row stride LDK=128:
//   horiz cube at entry ofs b*32768:        entry[u][r] = {img[ch][u][r], img[ch][u+1][r]}
//   vert  cube at entry ofs b*32768+16384:  entry[u][k] = {img[ch][k][u], img[ch][k][u+1]}
// (second tap clamped at the image edge; row u=127 is never read: i0<=126.)

#define CC 4
#define HH 128
#define WW 128
#define LDK 128              /* cube row stride, entries (16B each) */
#define CUBE (128 * LDK)     /* one direction cube, entries */

typedef _Float16 h2 __attribute__((ext_vector_type(2)));

__global__ void __launch_bounds__(256) fume_stage(
        const float* __restrict__ img, float4* __restrict__ ws) {
    __shared__ float tile[4][17][17];
    int x0 = blockIdx.x * 16, y0 = blockIdx.y * 16, b = blockIdx.z;
    int tx = threadIdx.x, ty = threadIdx.y;   // 16x16
    int id = ty * 16 + tx;
    const float* src = img + (size_t)b * CC * HH * WW;

    #pragma unroll
    for (int ch = 0; ch < 4; ++ch) {
        #pragma unroll
        for (int e = 0; e < 2; ++e) {
            int idx = id + e * 256;
            if (idx < 289) {
                int i = idx / 17, j = idx % 17;
                int r = min(y0 + i, HH - 1);
                int c = min(x0 + j, WW - 1);
                tile[ch][i][j] = src[(ch * HH + r) * WW + c];
            }
        }
    }
    __syncthreads();

    float4* base_h = ws + (size_t)b * (2 * CUBE);
    float4* base_v = base_h + CUBE;

    // horiz (transposed): entry[u = y0+ty][r = x0+tx] = {img[u][r], img[u+1][r]}
    //   taps tile[ch][ty][tx], tile[ch][ty+1][tx]; contiguous along tx.
    {
        h2 p0 = { (_Float16)tile[0][ty][tx], (_Float16)tile[0][ty + 1][tx] };
        h2 p1 = { (_Float16)tile[1][ty][tx], (_Float16)tile[1][ty + 1][tx] };
        h2 p2 = { (_Float16)tile[2][ty][tx], (_Float16)tile[2][ty + 1][tx] };
        h2 p3 = { (_Float16)tile[3][ty][tx], (_Float16)tile[3][ty + 1][tx] };
        float4 e = make_float4(__builtin_bit_cast(float, p0),
                               __builtin_bit_cast(float, p1),
                               __builtin_bit_cast(float, p2),
                               __builtin_bit_cast(float, p3));
        base_h[(y0 + ty) * LDK + (x0 + tx)] = e;
    }
    // vert (transposed): entry[u = x0+ty][k = y0+tx] = {img[k][u], img[k][u+1]}
    //   taps tile[ch][tx][ty], tile[ch][tx][ty+1]; contiguous along tx.
    //   (LDS read tile[ch][tx][ty]: stride 17 across lanes -> conflict-free.)
    {
        h2 p0 = { (_Float16)tile[0][tx][ty], (_Float16)tile[0][tx][ty + 1] };
        h2 p1 = { (_Float16)tile[1][tx][ty], (_Float16)tile[1][tx][ty + 1] };
        h2 p2 = { (_Float16)tile[2][tx][ty], (_Float16)tile[2][tx][ty + 1] };
        h2 p3 = { (_Float16)tile[3][tx][ty], (_Float16)tile[3][tx][ty + 1] };
        float4 e = make_float4(__builtin_bit_cast(float, p0),
                               __builtin_bit_cast(float, p1),
                               __builtin_bit_cast(float, p2),
                               __builtin_bit_cast(float, p3));
        base_v[(x0 + ty) * LDK + (y0 + tx)] = e;
    }
}

__global__ void __launch_bounds__(512) fume_kernel(
        const float4* __restrict__ cubes,
        const float* __restrict__ F,
        const float* __restrict__ dsf,
        float* __restrict__ out) {
    int j = threadIdx.x;                 // 0..63 : k-slot within the wave
    int w = threadIdx.y;                 // 0..7  : pixel (x) within block = wave id
    int x = blockIdx.x * 8 + w;
    int y = blockIdx.y;
    int b = blockIdx.z;

    float d = dsf[b];
    float F00 = F[0], F01 = F[1], F02 = F[2];
    float F10 = F[3], F11 = F[4], F12 = F[5];
    float F20 = F[6], F21 = F[7], F22 = F[8];

    // Exact reference op order (no fma contraction).
    float px = __fmul_rn((float)x, d);
    float py = __fmul_rn((float)y, d);
    float av = __fadd_rn(__fadd_rn(__fmul_rn(F00, px), __fmul_rn(F01, py)), F02);
    float bv = __fadd_rn(__fadd_rn(__fmul_rn(F10, px), __fmul_rn(F11, py)), F12);
    float cv = __fadd_rn(__fadd_rn(__fmul_rn(F20, px), __fmul_rn(F21, py)), F22);

    bool horiz  = fabsf(bv) >= fabsf(av);
    float ncoef = horiz ? av : bv;
    float den   = __fmul_rn(horiz ? bv : av, d);
    float nrec  = -__fdiv_rn(1.0f, den);   // den 0/Inf/NaN -> u NaN -> masked

    const float4* P = cubes + (size_t)b * (2 * CUBE) + (horiz ? 0 : CUBE);

    // Conservative valid-k interval (wave-uniform: all lanes same pixel).
    float A  = __fmul_rn(__fmul_rn(ncoef, d), nrec);
    float Bc = __fmul_rn(cv, nrec);
    int lkmin, lkmax;
    if (fabsf(A) > 1e-20f) {
        float inv = 1.0f / A;
        float k1 = (0.0f   - Bc) * inv;
        float k2 = (127.0f - Bc) * inv;
        float lo = fmaxf(fminf(k1, k2) - 2.0f, 0.0f);
        float hi = fminf(fmaxf(k1, k2) + 2.0f, 127.0f);
        if (lo > hi || !(lo == lo)) { lkmin = 1; lkmax = 0; }
        else { lkmin = (int)lo; lkmax = (int)hi; }
    } else {
        bool full = (Bc >= 0.0f) && (Bc <= 127.0f);
        lkmin = full ? 0 : 1;
        lkmax = full ? 127 : 0;
    }

    float a0 = 0.f, a1 = 0.f, a2 = 0.f, a3 = 0.f;
    // len <= 128 always -> at most 2 rounds of 64 k-slots.
    #pragma unroll
    for (int t = 0; t < 2; ++t) {
        int k = lkmin + (t << 6) + j;          // k >= lkmin always
        if (k <= lkmax) {                      // whole-wave skip when round empty
            float m  = __fmul_rn((float)k, d);
            float q  = __fadd_rn(__fmul_rn(ncoef, m), cv);
            float u  = __fmul_rn(q, nrec);
            bool ok  = (u >= 0.f) && (u <= 127.f);
            int i0   = (int)floorf(u);         // NaN->0, sat; clamped next
            i0 = max(0, min(i0, 126));
            float wq = __fsub_rn(u, (float)i0);    // ==1 at u==127 -> row[127]
            h2 wp = __builtin_bit_cast(h2,
                        __builtin_amdgcn_cvt_pkrtz(__fsub_rn(1.f, wq), wq));
            wp = ok ? wp : (h2){(_Float16)0.f, (_Float16)0.f};
            float4 e = P[i0 * LDK + k];
            a0 = __builtin_amdgcn_fdot2(wp, __builtin_bit_cast(h2, e.x), a0, false);
            a1 = __builtin_amdgcn_fdot2(wp, __builtin_bit_cast(h2, e.y), a1, false);
            a2 = __builtin_amdgcn_fdot2(wp, __builtin_bit_cast(h2, e.z), a2, false);
            a3 = __builtin_amdgcn_fdot2(wp, __builtin_bit_cast(h2, e.w), a3, false);
        }
    }

    // Wave xor-tree reduction over the 64 k-slots (deterministic order).
    #pragma unroll
    for (int mlt = 32; mlt >= 1; mlt >>= 1) {
        a0 = __fadd_rn(a0, __shfl_xor(a0, mlt));
        a1 = __fadd_rn(a1, __shfl_xor(a1, mlt));
        a2 = __fadd_rn(a2, __shfl_xor(a2, mlt));
        a3 = __fadd_rn(a3, __shfl_xor(a3, mlt));
    }

    if (j < 4) {
        float v = (j == 0) ? a0 : (j == 1) ? a1 : (j == 2) ? a2 : a3;
        out[(((size_t)b * CC + j) * HH + y) * WW + x] = v;
    }
}

extern "C" void kernel_launch(void* const* d_in, const int* in_sizes, int n_in,
                              void* d_out, int out_size, void* d_ws, size_t ws_size,
                              hipStream_t stream) {
    const float* view1 = (const float*)d_in[0];
    const float* F21   = (const float*)d_in[1];
    const float* dsf   = (const float*)d_in[3];

    const int B = in_sizes[3];

    dim3 stb(16, 16, 1);
    dim3 stg(WW / 16, HH / 16, B);
    fume_stage<<<stg, stb, 0, stream>>>(view1, (float4*)d_ws);

    dim3 ftb(64, 8, 1);
    dim3 ftg(WW / 8, HH, B);
    fume_kernel<<<ftg, ftb, 0, stream>>>((const float4*)d_ws, F21, dsf,
                                         (float*)d_out);
}

// Round 3
// 69.572 us; speedup vs baseline: 1.1401x; 1.1401x over previous
//
#include <hip/hip_runtime.h>

// FUME epipolar translation, fp32 in/out. B from in_sizes[3]; C,H,W = 4,128,128.
//
// R14: octet-per-pixel gather on the transposed cube.
//  - R11 (67.2us): 8 seg-waves x 64 pixels, per-lane k-intervals. Every wave-load
//    = 64 unrelated (k,i0) -> 64 distinct 64B lines -> ~8.4M line-requests, the
//    dominant main-kernel cost (~14-16us of TA/L2 serialization).
//  - R13 (79.3us, regressed): wave-per-pixel, 64-k rounds -> issued-work bloat for
//    short lines. BUT it validated the [u][k] cube layout + f32 reorder (absmax
//    unchanged 0.0625).
//  - R14: each wave = 8 pixels x 8 k-slots (octet). Octet reads 8 CONSECUTIVE k =
//    contiguous 16B entries in the [u][k] cube (runs broken only by slope) ->
//    ~3-5 lines/octet instead of 8 -> ~2x less line traffic. Issued lane-steps
//    per pixel = 8*ceil(len/8), same as R11; wave trip = ceil(max-of-8 len / 8)
//    <= R11's max-of-64. Octet shfl-tree reduction (no LDS, no barrier).
//  Per-step math bit-identical to R11/R12/R13; only summation order changes.
//
// Workspace (16B entries = {half2(tap0,tap1)}ch=0..3), row stride LDK=128:
//   horiz cube at entry ofs b*32768:        entry[u][s] = {img[ch][u][s], img[ch][u+1][s]}
//   vert  cube at entry ofs b*32768+16384:  entry[u][k] = {img[ch][k][u], img[ch][k][u+1]}
// (second tap clamped at the image edge; row u=127 is never read: i0<=126.)

#define CC 4
#define HH 128
#define WW 128
#define LDK 128              /* cube row stride, entries (16B each) */
#define CUBE (128 * LDK)     /* one direction cube, entries */

typedef _Float16 h2 __attribute__((ext_vector_type(2)));

__global__ void __launch_bounds__(256) fume_stage(
        const float* __restrict__ img, float4* __restrict__ ws) {
    __shared__ float tile[4][17][17];
    int x0 = blockIdx.x * 16, y0 = blockIdx.y * 16, b = blockIdx.z;
    int tx = threadIdx.x, ty = threadIdx.y;   // 16x16
    int id = ty * 16 + tx;
    const float* src = img + (size_t)b * CC * HH * WW;

    #pragma unroll
    for (int ch = 0; ch < 4; ++ch) {
        #pragma unroll
        for (int e = 0; e < 2; ++e) {
            int idx = id + e * 256;
            if (idx < 289) {
                int i = idx / 17, j = idx % 17;
                int r = min(y0 + i, HH - 1);
                int c = min(x0 + j, WW - 1);
                tile[ch][i][j] = src[(ch * HH + r) * WW + c];
            }
        }
    }
    __syncthreads();

    float4* base_h = ws + (size_t)b * (2 * CUBE);
    float4* base_v = base_h + CUBE;

    // horiz (transposed): entry[u = y0+ty][s = x0+tx] = {img[u][s], img[u+1][s]}
    {
        h2 p0 = { (_Float16)tile[0][ty][tx], (_Float16)tile[0][ty + 1][tx] };
        h2 p1 = { (_Float16)tile[1][ty][tx], (_Float16)tile[1][ty + 1][tx] };
        h2 p2 = { (_Float16)tile[2][ty][tx], (_Float16)tile[2][ty + 1][tx] };
        h2 p3 = { (_Float16)tile[3][ty][tx], (_Float16)tile[3][ty + 1][tx] };
        float4 e = make_float4(__builtin_bit_cast(float, p0),
                               __builtin_bit_cast(float, p1),
                               __builtin_bit_cast(float, p2),
                               __builtin_bit_cast(float, p3));
        base_h[(y0 + ty) * LDK + (x0 + tx)] = e;
    }
    // vert (transposed): entry[u = x0+ty][k = y0+tx] = {img[k][u], img[k][u+1]}
    {
        h2 p0 = { (_Float16)tile[0][tx][ty], (_Float16)tile[0][tx][ty + 1] };
        h2 p1 = { (_Float16)tile[1][tx][ty], (_Float16)tile[1][tx][ty + 1] };
        h2 p2 = { (_Float16)tile[2][tx][ty], (_Float16)tile[2][tx][ty + 1] };
        h2 p3 = { (_Float16)tile[3][tx][ty], (_Float16)tile[3][tx][ty + 1] };
        float4 e = make_float4(__builtin_bit_cast(float, p0),
                               __builtin_bit_cast(float, p1),
                               __builtin_bit_cast(float, p2),
                               __builtin_bit_cast(float, p3));
        base_v[(x0 + ty) * LDK + (y0 + tx)] = e;
    }
}

__global__ void __launch_bounds__(512) fume_kernel(
        const float4* __restrict__ cubes,
        const float* __restrict__ F,
        const float* __restrict__ dsf,
        float* __restrict__ out) {
    int lane = threadIdx.x;              // 0..63
    int sub  = lane & 7;                 // k-offset within octet
    int oct  = lane >> 3;                // pixel within wave (0..7)
    int w    = threadIdx.y;              // wave id (0..7)
    int x = blockIdx.x * 64 + w * 8 + oct;
    int y = blockIdx.y;
    int b = blockIdx.z;

    float d = dsf[b];
    float F00 = F[0], F01 = F[1], F02 = F[2];
    float F10 = F[3], F11 = F[4], F12 = F[5];
    float F20 = F[6], F21 = F[7], F22 = F[8];

    // Exact reference op order (no fma contraction). Per-pixel (octet-uniform).
    float px = __fmul_rn((float)x, d);
    float py = __fmul_rn((float)y, d);
    float av = __fadd_rn(__fadd_rn(__fmul_rn(F00, px), __fmul_rn(F01, py)), F02);
    float bv = __fadd_rn(__fadd_rn(__fmul_rn(F10, px), __fmul_rn(F11, py)), F12);
    float cv = __fadd_rn(__fadd_rn(__fmul_rn(F20, px), __fmul_rn(F21, py)), F22);

    bool horiz  = fabsf(bv) >= fabsf(av);
    float ncoef = horiz ? av : bv;
    float den   = __fmul_rn(horiz ? bv : av, d);
    float nrec  = -__fdiv_rn(1.0f, den);   // den 0/Inf/NaN -> u NaN -> masked

    const float4* P = cubes + (size_t)b * (2 * CUBE) + (horiz ? 0 : CUBE);

    // Conservative valid-k interval (octet-uniform; exact mask still applied).
    float A  = __fmul_rn(__fmul_rn(ncoef, d), nrec);
    float Bc = __fmul_rn(cv, nrec);
    int lkmin, lkmax;
    if (fabsf(A) > 1e-20f) {
        float inv = 1.0f / A;
        float k1 = (0.0f   - Bc) * inv;
        float k2 = (127.0f - Bc) * inv;
        float lo = fmaxf(fminf(k1, k2) - 2.0f, 0.0f);
        float hi = fminf(fmaxf(k1, k2) + 2.0f, 127.0f);
        if (lo > hi || !(lo == lo)) { lkmin = 1; lkmax = 0; }
        else { lkmin = (int)lo; lkmax = (int)hi; }
    } else {
        bool full = (Bc >= 0.0f) && (Bc <= 127.0f);
        lkmin = full ? 0 : 1;
        lkmax = full ? 127 : 0;
    }

    // Wave-uniform trip count = max over the 8 octets of ceil(len/8).
    int len = lkmax - lkmin + 1;          // may be <=0 (empty)
    int cnt = (len + 7) >> 3;
    int wm  = cnt;
    #pragma unroll
    for (int m = 1; m < 64; m <<= 1) wm = max(wm, __shfl_xor(wm, m));

    float a0 = 0.f, a1 = 0.f, a2 = 0.f, a3 = 0.f;
    for (int s = 0; s < wm; ++s) {
        int k = lkmin + (s << 3) + sub;   // octet covers 8 consecutive k
        if (k <= lkmax) {
            float m  = __fmul_rn((float)k, d);
            float q  = __fadd_rn(__fmul_rn(ncoef, m), cv);
            float u  = __fmul_rn(q, nrec);
            bool ok  = (u >= 0.f) && (u <= 127.f);
            int i0   = (int)floorf(u);    // NaN->0, sat; clamped next
            i0 = max(0, min(i0, 126));
            float wq = __fsub_rn(u, (float)i0);   // ==1 at u==127 -> row[127]
            h2 wp = __builtin_bit_cast(h2,
                        __builtin_amdgcn_cvt_pkrtz(__fsub_rn(1.f, wq), wq));
            wp = ok ? wp : (h2){(_Float16)0.f, (_Float16)0.f};
            float4 e = P[i0 * LDK + k];   // [u][k]: consecutive k contiguous
            a0 = __builtin_amdgcn_fdot2(wp, __builtin_bit_cast(h2, e.x), a0, false);
            a1 = __builtin_amdgcn_fdot2(wp, __builtin_bit_cast(h2, e.y), a1, false);
            a2 = __builtin_amdgcn_fdot2(wp, __builtin_bit_cast(h2, e.z), a2, false);
            a3 = __builtin_amdgcn_fdot2(wp, __builtin_bit_cast(h2, e.w), a3, false);
        }
    }

    // Octet tree-reduction over the 8 k-slots (deterministic order, no LDS).
    #pragma unroll
    for (int m = 1; m < 8; m <<= 1) {
        a0 = __fadd_rn(a0, __shfl_xor(a0, m));
        a1 = __fadd_rn(a1, __shfl_xor(a1, m));
        a2 = __fadd_rn(a2, __shfl_xor(a2, m));
        a3 = __fadd_rn(a3, __shfl_xor(a3, m));
    }

    if (sub < 4) {                        // lanes 0..3 of each octet: one ch each
        float v = (sub == 0) ? a0 : (sub == 1) ? a1 : (sub == 2) ? a2 : a3;
        out[(((size_t)b * CC + sub) * HH + y) * WW + x] = v;
    }
}

extern "C" void kernel_launch(void* const* d_in, const int* in_sizes, int n_in,
                              void* d_out, int out_size, void* d_ws, size_t ws_size,
                              hipStream_t stream) {
    const float* view1 = (const float*)d_in[0];
    const float* F21   = (const float*)d_in[1];
    const float* dsf   = (const float*)d_in[3];

    const int B = in_sizes[3];

    dim3 stb(16, 16, 1);
    dim3 stg(WW / 16, HH / 16, B);
    fume_stage<<<stg, stb, 0, stream>>>(view1, (float4*)d_ws);

    dim3 ftb(64, 8, 1);
    dim3 ftg(WW / 64, HH, B);
    fume_kernel<<<ftg, ftb, 0, stream>>>((const float4*)d_ws, F21, dsf,
                                         (float*)d_out);
}